// Round 1
// baseline (1851.151 us; speedup 1.0000x reference)
//
#include <hip/hip_runtime.h>

// FeatureAdaption: offset = shape @ w_off (1x1 conv), then DCNv1 deform conv + ReLU.
// B=8, Cin=Cout=256, H=W=64, G=4, Cg=64, K=3, K2=9, NGK=G*K2=36, NPIX=B*H*W=32768.

#define NPIX 32768
#define NGK  36

// ---------------- Kernel O: sampling positions ----------------
// posY/posX layout: [gk][pix]  (coalesced write here, coalesced read in kmain)
__global__ __launch_bounds__(256) void koff(const float* __restrict__ shape,
                                            const float* __restrict__ w_off,
                                            float* __restrict__ posY,
                                            float* __restrict__ posX) {
    __shared__ float wo[72 * 36];
    int tid = threadIdx.x;
    for (int i = tid; i < 72 * 36; i += 256) wo[i] = w_off[i];
    __syncthreads();

    int pix = blockIdx.x * 256 + tid;
    int b = pix >> 12, hw = pix & 4095;
    int h = hw >> 6, w = hw & 63;

    float s[36];
#pragma unroll
    for (int i = 0; i < 36; ++i) s[i] = shape[((b * 36 + i) << 12) + hw];

    for (int gk = 0; gk < 36; ++gk) {
        float oy = 0.f, ox = 0.f;
        const float* wy = &wo[(gk * 2 + 0) * 36];
        const float* wx = &wo[(gk * 2 + 1) * 36];
#pragma unroll
        for (int i = 0; i < 36; ++i) { oy += s[i] * wy[i]; ox += s[i] * wx[i]; }
        int k = gk % 9;
        posY[gk * NPIX + pix] = oy + (float)(k / 3 - 1) + (float)h;
        posX[gk * NPIX + pix] = ox + (float)(k % 3 - 1) + (float)w;
    }
}

// ---------------- Kernel W: transpose weights ----------------
// wT[(gk*64 + c)*256 + o] = w_def[(o*256 + g*64 + c)*9 + k]
__global__ __launch_bounds__(256) void kwt(const float* __restrict__ w_def,
                                           float* __restrict__ wT) {
    int idx = blockIdx.x * 256 + threadIdx.x;  // 2304*256 total
    int o = idx & 255;
    int r = idx >> 8;   // gk*64 + c
    int c = r & 63;
    int gk = r >> 6;
    int g = gk / 9, k = gk % 9;
    wT[idx] = w_def[(o * 256 + g * 64 + c) * 9 + k];
}

// ---------------- Kernel B: fused sampling + GEMM + ReLU ----------------
// One block = 32 consecutive pixels (same b, same row) x all 256 outputs.
// 256 threads: each owns outputs {2t&254, +1} over 16 pixels -> acc[2][16].
__global__ __launch_bounds__(256) void kmain(const float* __restrict__ x,
                                             const float* __restrict__ posY,
                                             const float* __restrict__ posX,
                                             const float* __restrict__ wT,
                                             float* __restrict__ out) {
    __shared__ float val[32 * 65];  // [pixel][c], pad 65 to avoid bank conflicts

    int tid = threadIdx.x;
    int pix_base = blockIdx.x * 32;
    int b = pix_base >> 12;
    int rowbase = pix_base & 4095;

    int p_s = tid & 31;            // sampling: pixel this thread samples for
    int cbase = (tid >> 5) * 8;    // sampling: channel range [cbase, cbase+8)

    int o0 = (tid & 127) * 2;      // GEMM: output channels o0, o0+1
    int pgrp = tid >> 7;           // GEMM: pixel half (0: 0-15, 1: 16-31)

    float acc0[16], acc1[16];
#pragma unroll
    for (int i = 0; i < 16; ++i) { acc0[i] = 0.f; acc1[i] = 0.f; }

    for (int gk = 0; gk < 36; ++gk) {
        int g = gk / 9;
        // ---- bilinear sampling for this (g,k) tap ----
        float py = posY[gk * NPIX + pix_base + p_s];
        float px = posX[gk * NPIX + pix_base + p_s];
        float y0f = floorf(py), x0f = floorf(px);
        int y0 = (int)y0f, x0 = (int)x0f;
        float fy = py - y0f, fx = px - x0f;
        int y1 = y0 + 1, x1 = x0 + 1;
        float m00 = (float)((y0 >= 0) && (y0 < 64) && (x0 >= 0) && (x0 < 64));
        float m01 = (float)((y0 >= 0) && (y0 < 64) && (x1 >= 0) && (x1 < 64));
        float m10 = (float)((y1 >= 0) && (y1 < 64) && (x0 >= 0) && (x0 < 64));
        float m11 = (float)((y1 >= 0) && (y1 < 64) && (x1 >= 0) && (x1 < 64));
        float w00 = (1.f - fy) * (1.f - fx) * m00;
        float w01 = (1.f - fy) * fx * m01;
        float w10 = fy * (1.f - fx) * m10;
        float w11 = fy * fx * m11;
        int yc0 = min(max(y0, 0), 63), yc1 = min(max(y1, 0), 63);
        int xc0 = min(max(x0, 0), 63), xc1 = min(max(x1, 0), 63);
        int a00 = yc0 * 64 + xc0, a01 = yc0 * 64 + xc1;
        int a10 = yc1 * 64 + xc0, a11 = yc1 * 64 + xc1;

        const float* xb = x + (((b * 4 + g) * 64 + cbase) << 12);
#pragma unroll
        for (int cc = 0; cc < 8; ++cc) {
            const float* ch = xb + (cc << 12);
            float v = w00 * ch[a00] + w01 * ch[a01] + w10 * ch[a10] + w11 * ch[a11];
            val[p_s * 65 + cbase + cc] = v;
        }
        __syncthreads();

        // ---- GEMM micro-step over this tap's 64 channels ----
        const float* wp = wT + gk * 64 * 256 + o0;
        const float* vp = val + pgrp * 16 * 65;
#pragma unroll 8
        for (int c = 0; c < 64; ++c) {
            float2 wv = *(const float2*)(wp + c * 256);
#pragma unroll
            for (int pp = 0; pp < 16; ++pp) {
                float v = vp[pp * 65 + c];
                acc0[pp] += v * wv.x;
                acc1[pp] += v * wv.y;
            }
        }
        __syncthreads();
    }

    // ---- epilogue: ReLU + store ----
    int p0 = pgrp * 16;
    float* r0 = out + ((b * 256 + o0) << 12) + rowbase + p0;
    float* r1 = out + ((b * 256 + o0 + 1) << 12) + rowbase + p0;
#pragma unroll
    for (int pp = 0; pp < 16; ++pp) {
        r0[pp] = fmaxf(acc0[pp], 0.f);
        r1[pp] = fmaxf(acc1[pp], 0.f);
    }
}

extern "C" void kernel_launch(void* const* d_in, const int* in_sizes, int n_in,
                              void* d_out, int out_size, void* d_ws, size_t ws_size,
                              hipStream_t stream) {
    const float* x     = (const float*)d_in[0];
    const float* shape = (const float*)d_in[1];
    const float* w_off = (const float*)d_in[2];
    const float* w_def = (const float*)d_in[3];
    float* out = (float*)d_out;

    float* posY = (float*)d_ws;                     // 36*32768 floats
    float* posX = posY + NGK * NPIX;                // 36*32768 floats
    float* wT   = posX + NGK * NPIX;                // 2304*256 floats

    koff<<<NPIX / 256, 256, 0, stream>>>(shape, w_off, posY, posX);
    kwt<<<2304, 256, 0, stream>>>(w_def, wT);
    kmain<<<NPIX / 32, 256, 0, stream>>>(x, posY, posX, wT, out);
}

// Round 2
// 115.730 us; speedup vs baseline: 15.9954x; 15.9954x over previous
//
#include <hip/hip_runtime.h>

// FeatureAdaption on MI355X: offset = shape @ w_off (1x1), DCNv1 deform conv + ReLU.
// B=8, Cin=Cout=256, H=W=64, G=4, Cg=64, K=3, K2=9, NGK=36, NPIX=32768.
// Plan: koff -> sampling positions; kxt -> channels-last bf16 xT[b][g][y][x][c];
// kwb -> bf16 weights wB[gk][o][c] with XOR-swizzle baked in; kmain -> fused
// bilinear sampling + bf16 MFMA GEMM (M=o 256, N=pix 64/tile, K=36*64), ReLU.

#define NPIX 32768
#define NGK  36
#define HW   4096

typedef __attribute__((ext_vector_type(8))) short short8;
typedef __attribute__((ext_vector_type(4))) float f32x4;
typedef unsigned short u16;

__device__ __forceinline__ float bf2f(u16 s) {
    union { unsigned u; float f; } cv;
    cv.u = ((unsigned)s) << 16;
    return cv.f;
}
__device__ __forceinline__ u16 f2bf(float f) {
    union { float f; unsigned u; } cv;
    cv.f = f;
    unsigned u = cv.u + 0x7FFFu + ((cv.u >> 16) & 1u);
    return (u16)(u >> 16);
}
__device__ __forceinline__ void async_cp16(const void* g, void* l) {
    __builtin_amdgcn_global_load_lds(
        (const __attribute__((address_space(1))) void*)g,
        (__attribute__((address_space(3))) void*)l, 16, 0, 0);
}

// ---------------- Kernel O: sampling positions, [gk][pix] ----------------
__global__ __launch_bounds__(256) void koff(const float* __restrict__ shape,
                                            const float* __restrict__ w_off,
                                            float* __restrict__ posY,
                                            float* __restrict__ posX) {
    __shared__ float wo[72 * 36];
    int tid = threadIdx.x;
    for (int i = tid; i < 72 * 36; i += 256) wo[i] = w_off[i];
    __syncthreads();

    int pix = blockIdx.x * 256 + tid;
    int b = pix >> 12, hw = pix & 4095;
    int h = hw >> 6, w = hw & 63;

    float s[36];
#pragma unroll
    for (int i = 0; i < 36; ++i) s[i] = shape[((b * 36 + i) << 12) + hw];

    for (int gk = 0; gk < 36; ++gk) {
        float oy = 0.f, ox = 0.f;
        const float* wy = &wo[(gk * 2 + 0) * 36];
        const float* wx = &wo[(gk * 2 + 1) * 36];
#pragma unroll
        for (int i = 0; i < 36; ++i) { oy += s[i] * wy[i]; ox += s[i] * wx[i]; }
        int k = gk % 9;
        posY[gk * NPIX + pix] = oy + (float)(k / 3 - 1) + (float)h;
        posX[gk * NPIX + pix] = ox + (float)(k % 3 - 1) + (float)w;
    }
}

// ---------------- Kernel X: x (B,256,H,W) fp32 -> xT[b][g][hw][c] bf16 ----------------
__global__ __launch_bounds__(256) void kxt(const float* __restrict__ x,
                                           u16* __restrict__ xT) {
    __shared__ float tile[64][65];
    int tid = threadIdx.x;
    int bg  = blockIdx.x >> 6;          // b*4+g
    int hw0 = (blockIdx.x & 63) << 6;
    int hwo = tid & 63;
#pragma unroll
    for (int i = 0; i < 16; ++i) {
        int c = (tid >> 6) + (i << 2);
        tile[c][hwo] = x[((bg << 6) + c) * HW + hw0 + hwo];
    }
    __syncthreads();
    int hw = tid >> 2;
    int cb4 = (tid & 3) << 4;
    short8 r0, r1;
#pragma unroll
    for (int j = 0; j < 8; ++j) {
        r0[j] = (short)f2bf(tile[cb4 + j][hw]);
        r1[j] = (short)f2bf(tile[cb4 + 8 + j][hw]);
    }
    u16* dst = xT + (((bg << 12) + hw0 + hw) << 6) + cb4;
    *(short8*)dst = r0;
    *(short8*)(dst + 8) = r1;
}

// ---------------- Kernel W: wB[gk][o][c ^ ((o&7)<<3)] = bf16(w_def[o][g*64+c][k]) ----------------
__global__ __launch_bounds__(256) void kwb(const float* __restrict__ w_def,
                                           u16* __restrict__ wB) {
    int idx = blockIdx.x * 256 + threadIdx.x;  // 36*256*64 = 589824
    int c = idx & 63;
    int o = (idx >> 6) & 255;
    int gk = idx >> 14;
    int g = gk / 9, k = gk - g * 9;
    float v = w_def[((o << 8) + (g << 6) + c) * 9 + k];
    wB[(gk << 14) + (o << 6) + (c ^ ((o & 7) << 3))] = f2bf(v);
}

// ---------------- main: fused sampling + MFMA GEMM + ReLU ----------------
struct Samp {
    short8 v00, v01, v10, v11;
    float w00, w01, w10, w11;
    int dst;
};

__device__ __forceinline__ Samp sample_issue(
    int gk, int g, int pixbase, int b,
    const float* __restrict__ posY, const float* __restrict__ posX,
    const u16* __restrict__ xT, int sp, int sck)
{
    Samp s;
    int pix = pixbase + sp;
    float py = posY[gk * NPIX + pix];
    float px = posX[gk * NPIX + pix];
    float y0f = floorf(py), x0f = floorf(px);
    float fy = py - y0f, fx = px - x0f;
    int y0 = (int)y0f, x0 = (int)x0f;
    int y1 = y0 + 1, x1 = x0 + 1;
    float vy0 = (y0 >= 0 && y0 < 64) ? 1.f : 0.f;
    float vy1 = (y1 >= 0 && y1 < 64) ? 1.f : 0.f;
    float vx0 = (x0 >= 0 && x0 < 64) ? 1.f : 0.f;
    float vx1 = (x1 >= 0 && x1 < 64) ? 1.f : 0.f;
    s.w00 = (1.f - fy) * (1.f - fx) * vy0 * vx0;
    s.w01 = (1.f - fy) * fx * vy0 * vx1;
    s.w10 = fy * (1.f - fx) * vy1 * vx0;
    s.w11 = fy * fx * vy1 * vx1;
    int yc0 = min(max(y0, 0), 63), yc1 = min(max(y1, 0), 63);
    int xc0 = min(max(x0, 0), 63), xc1 = min(max(x1, 0), 63);
    const u16* base = xT + (((b << 2) + g) << 18) + (sck << 3);
    s.v00 = *(const short8*)(base + (((yc0 << 6) + xc0) << 6));
    s.v01 = *(const short8*)(base + (((yc0 << 6) + xc1) << 6));
    s.v10 = *(const short8*)(base + (((yc1 << 6) + xc0) << 6));
    s.v11 = *(const short8*)(base + (((yc1 << 6) + xc1) << 6));
    s.dst = (sp << 6) + ((sck ^ (sp & 7)) << 3);   // XOR-swizzled A-tile slot
    return s;
}

__device__ __forceinline__ void sample_finish(const Samp& s, u16* sVb) {
    short8 r;
#pragma unroll
    for (int i = 0; i < 8; ++i) {
        float v = s.w00 * bf2f((u16)s.v00[i]) + s.w01 * bf2f((u16)s.v01[i])
                + s.w10 * bf2f((u16)s.v10[i]) + s.w11 * bf2f((u16)s.v11[i]);
        r[i] = (short)f2bf(v);
    }
    *(short8*)(sVb + s.dst) = r;
}

__global__ __launch_bounds__(512, 4) void kmain(
    const u16* __restrict__ xT,
    const float* __restrict__ posY, const float* __restrict__ posX,
    const u16* __restrict__ wB, float* __restrict__ out)
{
    __shared__ __align__(16) u16 sW[2][256 * 64];  // weights tile, 32KB each
    __shared__ __align__(16) u16 sV[2][64 * 64];   // sampled-values tile, 8KB each

    int tid = threadIdx.x;
    int pixbase = blockIdx.x << 6;   // 64 pixels per block, never straddles b
    int b = pixbase >> 12;

    // sampling roles: 64 px x 8 channel-chunks
    int sp = tid >> 3, sck = tid & 7;
    // compute roles: 8 waves = 4 o-slices x 2 px-slices
    int lane = tid & 63, wid = tid >> 6;
    int o0 = (wid & 3) << 6;
    int p0 = (wid >> 2) << 5;

    f32x4 acc[4][2];
#pragma unroll
    for (int i = 0; i < 4; ++i)
#pragma unroll
        for (int j = 0; j < 2; ++j)
            acc[i][j] = (f32x4){0.f, 0.f, 0.f, 0.f};

    // ---- prologue: stage W0 + sample tap 0 ----
    {
#pragma unroll
        for (int r = 0; r < 4; ++r)
            async_cp16(wB + (r << 12) + (tid << 3), &sW[0][(r << 12) + (tid << 3)]);
        Samp s = sample_issue(0, 0, pixbase, b, posY, posX, xT, sp, sck);
        sample_finish(s, sV[0]);
    }
    __syncthreads();

    for (int t = 0; t < NGK; ++t) {
        int cb = t & 1, nb = cb ^ 1;
        Samp s;
        bool hn = (t < NGK - 1);
        if (hn) {
            // prefetch next tap: weights -> LDS (async), gathers -> VGPRs
            const u16* wsrc = wB + ((t + 1) << 14);
#pragma unroll
            for (int r = 0; r < 4; ++r)
                async_cp16(wsrc + (r << 12) + (tid << 3), &sW[nb][(r << 12) + (tid << 3)]);
            s = sample_issue(t + 1, (t + 1) / 9, pixbase, b, posY, posX, xT, sp, sck);
        }

        // ---- MFMA on current buffers ----
        const u16* Wb = sW[cb];
        const u16* Vb = sV[cb];
#pragma unroll
        for (int kc = 0; kc < 2; ++kc) {
            int c0 = (kc << 5) + ((lane >> 4) << 3);
            int cs = c0 ^ ((lane & 7) << 3);       // (row&7)<<3 XOR swizzle
            short8 af[4], bfr[2];
#pragma unroll
            for (int of = 0; of < 4; ++of) {
                int o = o0 + (of << 4) + (lane & 15);
                af[of] = *(const short8*)(Wb + (o << 6) + cs);
            }
#pragma unroll
            for (int pf = 0; pf < 2; ++pf) {
                int p = p0 + (pf << 4) + (lane & 15);
                bfr[pf] = *(const short8*)(Vb + (p << 6) + cs);
            }
#pragma unroll
            for (int of = 0; of < 4; ++of)
#pragma unroll
                for (int pf = 0; pf < 2; ++pf)
                    acc[of][pf] = __builtin_amdgcn_mfma_f32_16x16x32_bf16(
                        af[of], bfr[pf], acc[of][pf], 0, 0, 0);
        }

        if (hn) sample_finish(s, sV[nb]);
        __syncthreads();
    }

    // ---- epilogue: ReLU + store (16-lane-contiguous 64B segments) ----
    int hwb = (pixbase & 4095) + p0;
    int obase = (b << 8) + o0 + ((lane >> 4) << 2);
#pragma unroll
    for (int of = 0; of < 4; ++of) {
#pragma unroll
        for (int pf = 0; pf < 2; ++pf) {
            float* op = out + ((obase + (of << 4)) << 12) + hwb + (pf << 4) + (lane & 15);
#pragma unroll
            for (int r = 0; r < 4; ++r)
                op[r << 12] = fmaxf(acc[of][pf][r], 0.f);
        }
    }
}

extern "C" void kernel_launch(void* const* d_in, const int* in_sizes, int n_in,
                              void* d_out, int out_size, void* d_ws, size_t ws_size,
                              hipStream_t stream) {
    const float* x     = (const float*)d_in[0];
    const float* shape = (const float*)d_in[1];
    const float* w_off = (const float*)d_in[2];
    const float* w_def = (const float*)d_in[3];
    float* out = (float*)d_out;

    float* posY = (float*)d_ws;                       // 36*32768 f32 = 4.72 MB
    float* posX = posY + NGK * NPIX;                  // 4.72 MB
    u16*   wB   = (u16*)(posX + NGK * NPIX);          // 36*256*64 bf16 = 1.18 MB
    u16*   xT   = wB + NGK * 256 * 64;                // 8*4*4096*64 bf16 = 16.8 MB

    koff<<<NPIX / 256, 256, 0, stream>>>(shape, w_off, posY, posX);
    kxt<<<2048, 256, 0, stream>>>(x, xT);
    kwb<<<2304, 256, 0, stream>>>(w_def, wB);
    kmain<<<512, 512, 0, stream>>>(xT, posY, posX, wB, out);
}

// Round 3
// 109.367 us; speedup vs baseline: 16.9260x; 1.0582x over previous
//
#include <hip/hip_runtime.h>
#include <hip/hip_bf16.h>

// FeatureAdaption on MI355X: offset = shape @ w_off (1x1), DCNv1 deform conv + ReLU.
// B=8, Cin=Cout=256, H=W=64, G=4, Cg=64, K=3, K2=9, NGK=36, NPIX=32768.
// koff -> float2 sampling positions; kxt -> channels-last bf16 xT[b][g][hw][c];
// kwb -> bf16 weights wB[gk][o][c] XOR-swizzled; kmain -> fused bilinear sampling
// (2-tap-ahead gather pipeline) + bf16 MFMA GEMM + ReLU.

#define NPIX 32768
#define NGK  36
#define HW   4096

typedef __attribute__((ext_vector_type(8))) short short8;
typedef __attribute__((ext_vector_type(4))) float f32x4;
typedef unsigned short u16;
typedef unsigned int u32;

__device__ __forceinline__ float bfu_lo(u32 u) {
    union { u32 u; float f; } cv; cv.u = u << 16; return cv.f;
}
__device__ __forceinline__ float bfu_hi(u32 u) {
    union { u32 u; float f; } cv; cv.u = u & 0xFFFF0000u; return cv.f;
}
__device__ __forceinline__ u16 f2bf(float f) {
    union { float f; u32 u; } cv;
    cv.f = f;
    u32 u = cv.u + 0x7FFFu + ((cv.u >> 16) & 1u);
    return (u16)(u >> 16);
}
__device__ __forceinline__ void async_cp16(const void* g, void* l) {
    __builtin_amdgcn_global_load_lds(
        (const __attribute__((address_space(1))) void*)g,
        (__attribute__((address_space(3))) void*)l, 16, 0, 0);
}

// ---------------- Kernel O: sampling positions, float2 [gk][pix] ----------------
__global__ __launch_bounds__(256) void koff(const float* __restrict__ shape,
                                            const float* __restrict__ w_off,
                                            float2* __restrict__ pos) {
    __shared__ float wo[72 * 36];
    int tid = threadIdx.x;
    for (int i = tid; i < 72 * 36; i += 256) wo[i] = w_off[i];
    __syncthreads();

    int pix = blockIdx.x * 256 + tid;
    int b = pix >> 12, hw = pix & 4095;
    int h = hw >> 6, w = hw & 63;

    float s[36];
#pragma unroll
    for (int i = 0; i < 36; ++i) s[i] = shape[((b * 36 + i) << 12) + hw];

    for (int gk = 0; gk < 36; ++gk) {
        float oy = 0.f, ox = 0.f;
        const float* wy = &wo[(gk * 2 + 0) * 36];
        const float* wx = &wo[(gk * 2 + 1) * 36];
#pragma unroll
        for (int i = 0; i < 36; ++i) { oy += s[i] * wy[i]; ox += s[i] * wx[i]; }
        int k = gk % 9;
        pos[gk * NPIX + pix] = make_float2(oy + (float)(k / 3 - 1) + (float)h,
                                           ox + (float)(k % 3 - 1) + (float)w);
    }
}

// ---------------- Kernel X: x (B,256,H,W) fp32 -> xT[b][g][hw][c] bf16 ----------------
__global__ __launch_bounds__(256) void kxt(const float* __restrict__ x,
                                           u16* __restrict__ xT) {
    __shared__ float tile[64][65];
    int tid = threadIdx.x;
    int bg  = blockIdx.x >> 6;          // b*4+g
    int hw0 = (blockIdx.x & 63) << 6;
    int hwo = tid & 63;
#pragma unroll
    for (int i = 0; i < 16; ++i) {
        int c = (tid >> 6) + (i << 2);
        tile[c][hwo] = x[((bg << 6) + c) * HW + hw0 + hwo];
    }
    __syncthreads();
    int hw = tid >> 2;
    int cb4 = (tid & 3) << 4;
    short8 r0, r1;
#pragma unroll
    for (int j = 0; j < 8; ++j) {
        r0[j] = (short)f2bf(tile[cb4 + j][hw]);
        r1[j] = (short)f2bf(tile[cb4 + 8 + j][hw]);
    }
    u16* dst = xT + (((bg << 12) + hw0 + hw) << 6) + cb4;
    *(short8*)dst = r0;
    *(short8*)(dst + 8) = r1;
}

// ---------------- Kernel W: wB[gk][o][c ^ ((o&7)<<3)] = bf16(w_def[o][g*64+c][k]) ----------------
__global__ __launch_bounds__(256) void kwb(const float* __restrict__ w_def,
                                           u16* __restrict__ wB) {
    int idx = blockIdx.x * 256 + threadIdx.x;  // 36*256*64 = 589824
    int c = idx & 63;
    int o = (idx >> 6) & 255;
    int gk = idx >> 14;
    int g = gk / 9, k = gk - g * 9;
    float v = w_def[((o << 8) + (g << 6) + c) * 9 + k];
    wB[(gk << 14) + (o << 6) + (c ^ ((o & 7) << 3))] = f2bf(v);
}

// ---------------- main: fused sampling + MFMA GEMM + ReLU ----------------
struct Samp {
    short8 v00, v01, v10, v11;
    float w00, w01, w10, w11;
    int dst;
};

__device__ __forceinline__ Samp sample_issue(
    int gk, int g, int pixbase, int b,
    const float2* __restrict__ pos,
    const u16* __restrict__ xT, int sp, int sck)
{
    Samp s;
    int pix = pixbase + sp;
    float2 p = pos[gk * NPIX + pix];
    float py = p.x, px = p.y;
    float y0f = floorf(py), x0f = floorf(px);
    float fy = py - y0f, fx = px - x0f;
    int y0 = (int)y0f, x0 = (int)x0f;
    int y1 = y0 + 1, x1 = x0 + 1;
    float vy0 = (y0 >= 0 && y0 < 64) ? 1.f : 0.f;
    float vy1 = (y1 >= 0 && y1 < 64) ? 1.f : 0.f;
    float vx0 = (x0 >= 0 && x0 < 64) ? 1.f : 0.f;
    float vx1 = (x1 >= 0 && x1 < 64) ? 1.f : 0.f;
    s.w00 = (1.f - fy) * (1.f - fx) * vy0 * vx0;
    s.w01 = (1.f - fy) * fx * vy0 * vx1;
    s.w10 = fy * (1.f - fx) * vy1 * vx0;
    s.w11 = fy * fx * vy1 * vx1;
    int yc0 = min(max(y0, 0), 63), yc1 = min(max(y1, 0), 63);
    int xc0 = min(max(x0, 0), 63), xc1 = min(max(x1, 0), 63);
    const u16* base = xT + (((b << 2) + g) << 18) + (sck << 3);
    s.v00 = *(const short8*)(base + (((yc0 << 6) + xc0) << 6));
    s.v01 = *(const short8*)(base + (((yc0 << 6) + xc1) << 6));
    s.v10 = *(const short8*)(base + (((yc1 << 6) + xc0) << 6));
    s.v11 = *(const short8*)(base + (((yc1 << 6) + xc1) << 6));
    s.dst = (sp << 6) + ((sck ^ (sp & 7)) << 3);   // XOR-swizzled slot
    return s;
}

__device__ __forceinline__ void sample_finish(const Samp& s, u16* sVb) {
    union { short8 s8; u32 u[4]; } A, Bc, C, D;
    A.s8 = s.v00; Bc.s8 = s.v01; C.s8 = s.v10; D.s8 = s.v11;
    u32 outw[4];
#pragma unroll
    for (int j = 0; j < 4; ++j) {
        // two independent FMA chains per element, pack pair with cvt_pk
        float lo0 = fmaf(s.w00, bfu_lo(A.u[j]), s.w01 * bfu_lo(Bc.u[j]));
        float lo1 = fmaf(s.w10, bfu_lo(C.u[j]), s.w11 * bfu_lo(D.u[j]));
        float hi0 = fmaf(s.w00, bfu_hi(A.u[j]), s.w01 * bfu_hi(Bc.u[j]));
        float hi1 = fmaf(s.w10, bfu_hi(C.u[j]), s.w11 * bfu_hi(D.u[j]));
        __hip_bfloat162 pk = __float22bfloat162_rn(make_float2(lo0 + lo1, hi0 + hi1));
        union { __hip_bfloat162 b; u32 u; } cv; cv.b = pk;
        outw[j] = cv.u;
    }
    union { u32 u[4]; short8 s8; } R;
#pragma unroll
    for (int j = 0; j < 4; ++j) R.u[j] = outw[j];
    *(short8*)(sVb + s.dst) = R.s8;
}

__device__ __forceinline__ void mfma_phase(
    const u16* __restrict__ Wb, const u16* __restrict__ Vb,
    int lane, int o0, int p0, f32x4 acc[4][2])
{
    __builtin_amdgcn_s_setprio(1);
#pragma unroll
    for (int kc = 0; kc < 2; ++kc) {
        int c0 = (kc << 5) + ((lane >> 4) << 3);
        int cs = c0 ^ ((lane & 7) << 3);
        short8 af[4], bfr[2];
#pragma unroll
        for (int of = 0; of < 4; ++of) {
            int o = o0 + (of << 4) + (lane & 15);
            af[of] = *(const short8*)(Wb + (o << 6) + cs);
        }
#pragma unroll
        for (int pf = 0; pf < 2; ++pf) {
            int p = p0 + (pf << 4) + (lane & 15);
            bfr[pf] = *(const short8*)(Vb + (p << 6) + cs);
        }
#pragma unroll
        for (int of = 0; of < 4; ++of)
#pragma unroll
            for (int pf = 0; pf < 2; ++pf)
                acc[of][pf] = __builtin_amdgcn_mfma_f32_16x16x32_bf16(
                    af[of], bfr[pf], acc[of][pf], 0, 0, 0);
    }
    __builtin_amdgcn_s_setprio(0);
}

__global__ __launch_bounds__(512, 4) void kmain(
    const u16* __restrict__ xT,
    const float2* __restrict__ pos,
    const u16* __restrict__ wB, float* __restrict__ out)
{
    __shared__ __align__(16) u16 sW[2][256 * 64];  // weights tile, 32KB each
    __shared__ __align__(16) u16 sV[2][64 * 64];   // sampled-values tile, 8KB each

    int tid = threadIdx.x;
    int pixbase = blockIdx.x << 6;   // 64 pixels per block
    int b = pixbase >> 12;

    int sp = tid >> 3, sck = tid & 7;        // sampling roles
    int lane = tid & 63, wid = tid >> 6;     // compute roles
    int o0 = (wid & 3) << 6;
    int p0 = (wid >> 2) << 5;

    f32x4 acc[4][2];
#pragma unroll
    for (int i = 0; i < 4; ++i)
#pragma unroll
        for (int j = 0; j < 2; ++j)
            acc[i][j] = (f32x4){0.f, 0.f, 0.f, 0.f};

    Samp sA, sB;

    // ---- prologue: stage W0; sample+finish tap0; issue tap1 ----
    {
#pragma unroll
        for (int r = 0; r < 4; ++r)
            async_cp16(wB + (r << 12) + (tid << 3), &sW[0][(r << 12) + (tid << 3)]);
        Samp s0 = sample_issue(0, 0, pixbase, b, pos, xT, sp, sck);
        sample_finish(s0, sV[0]);
        sA = sample_issue(1, 0, pixbase, b, pos, xT, sp, sck);
    }
    __syncthreads();

    // body(t): stage sW for t+1; issue samples t+2; MFMA on t; finish samples t+1.
#define TAP_BODY(T, SFIN, SISS)                                                  \
    {                                                                            \
        const int t_ = (T);                                                      \
        int cb = t_ & 1, nb = cb ^ 1;                                            \
        if (t_ + 1 < NGK) {                                                      \
            const u16* wsrc = wB + ((t_ + 1) << 14);                             \
            _Pragma("unroll")                                                    \
            for (int r = 0; r < 4; ++r)                                          \
                async_cp16(wsrc + (r << 12) + (tid << 3),                        \
                           &sW[nb][(r << 12) + (tid << 3)]);                     \
        }                                                                        \
        if (t_ + 2 < NGK)                                                        \
            SISS = sample_issue(t_ + 2, (t_ + 2) / 9, pixbase, b, pos, xT, sp, sck); \
        mfma_phase(sW[cb], sV[cb], lane, o0, p0, acc);                           \
        if (t_ + 1 < NGK) sample_finish(SFIN, sV[nb]);                           \
        __syncthreads();                                                         \
    }

    for (int t = 0; t < NGK; t += 2) {
        TAP_BODY(t,     sA, sB)
        TAP_BODY(t + 1, sB, sA)
    }
#undef TAP_BODY

    // ---- epilogue: ReLU + store ----
    int hwb = (pixbase & 4095) + p0;
    int obase = (b << 8) + o0 + ((lane >> 4) << 2);
#pragma unroll
    for (int of = 0; of < 4; ++of) {
#pragma unroll
        for (int pf = 0; pf < 2; ++pf) {
            float* op = out + ((obase + (of << 4)) << 12) + hwb + (pf << 4) + (lane & 15);
#pragma unroll
            for (int r = 0; r < 4; ++r)
                op[r << 12] = fmaxf(acc[of][pf][r], 0.f);
        }
    }
}

extern "C" void kernel_launch(void* const* d_in, const int* in_sizes, int n_in,
                              void* d_out, int out_size, void* d_ws, size_t ws_size,
                              hipStream_t stream) {
    const float* x     = (const float*)d_in[0];
    const float* shape = (const float*)d_in[1];
    const float* w_off = (const float*)d_in[2];
    const float* w_def = (const float*)d_in[3];
    float* out = (float*)d_out;

    float2* pos = (float2*)d_ws;                      // 36*32768 float2 = 9.4 MB
    u16*    wB  = (u16*)(pos + NGK * NPIX);           // 36*256*64 bf16 = 1.18 MB
    u16*    xT  = wB + NGK * 256 * 64;                // 8*4*4096*64 bf16 = 16.8 MB

    koff<<<NPIX / 256, 256, 0, stream>>>(shape, w_off, pos);
    kxt<<<2048, 256, 0, stream>>>(x, xT);
    kwb<<<2304, 256, 0, stream>>>(w_def, wB);
    kmain<<<512, 512, 0, stream>>>(xT, pos, wB, out);
}